// Round 1
// baseline (3564.577 us; speedup 1.0000x reference)
//
#include <hip/hip_runtime.h>

// FPS: input [8, 65536, 3] f32 -> (idx [8,1024] as f32 values, sampled [8,1024,3] f32)
// concatenated flat in d_out.
//
// R15 = R14 protocol minus barrier2: ALL 8 waves poll the 32 records and
// compute the global winner redundantly, so:
//   - barrier2 + LDS bc4/bn2 broadcast removed (each wave resumes the moment
//     it sees the tag -> no convoy through a second 8-wave barrier)
//   - publisher's store drain (incl. agent/IF mirror, ~coherence-point
//     latency) moves to the NEXT barrier1, hidden under poll+distance
//   - records switched AoS->SoA: three 32x8B word arrays per (batch,parity)
//     so a wave's 32-lane poll load coalesces into ~4 TCC requests/instr
//     (AoS 128B-stride records would be 32 uncoalesced requests x 8 waves)
//
// LDS red[] reuse is safe without barrier2: wave w can only write red[w] for
// t+1 after its poll(t) hit, which requires wave1's publish(t), which happens
// after wave1 read red for t (tag transitivity through barrier1).
//
// Ties resolve to the smallest global index (numpy argmax first-occurrence);
// distances are uncontracted fp32 in reference order -> bit-exact.
// Records: 3x 8B self-tagged words (round tag in low16 of each), parity
// double-buffered; stale L2 lines can't fake a future tag; per-word tags
// make mixed-age words harmless. IF fallback (wave-uniform, 128-double-iter
// timeout) keeps correctness independent of block->XCD placement.

#define NB    8
#define NPTS  65536
#define NSAMP 1024
#define WPB   32     // workgroups per batch (one XCD at 256 blocks)
#define TPB   512    // threads per workgroup (8 waves)
#define NWAVE 8
#define PPT   4      // points per thread (WPB*TPB*PPT == NPTS)
#define WSTR  32     // ull stride between the 3 word-arrays of one parity slot

typedef unsigned long long ull;

#define DPP(x, ctrl) \
  ((unsigned)__builtin_amdgcn_update_dpp((int)(x), (int)(x), (ctrl), 0xf, 0xf, false))

// max over 64 lanes -> uniform; row_shr:N = 0x110|N, bcast15=0x142, bcast31=0x143
__device__ __forceinline__ unsigned umax_wave64(unsigned x) {
  unsigned t;
  t = DPP(x, 0x111); x = t > x ? t : x;
  t = DPP(x, 0x112); x = t > x ? t : x;
  t = DPP(x, 0x114); x = t > x ? t : x;
  t = DPP(x, 0x118); x = t > x ? t : x;
  t = DPP(x, 0x142); x = t > x ? t : x;   // bcast15: row r lane15 -> row r+1
  t = DPP(x, 0x143); x = t > x ? t : x;   // bcast31: lane31 -> rows 2,3
  return (unsigned)__builtin_amdgcn_readlane((int)x, 63);
}
// max over lanes 0..7 -> uniform via lane7 (groups of 16 see their row's shr)
__device__ __forceinline__ unsigned umax_low8(unsigned x) {
  unsigned t;
  t = DPP(x, 0x111); x = t > x ? t : x;
  t = DPP(x, 0x112); x = t > x ? t : x;
  t = DPP(x, 0x114); x = t > x ? t : x;
  return (unsigned)__builtin_amdgcn_readlane((int)x, 7);
}

// 3x 8B loads from the three SoA word arrays (+0, +256B, +512B), NO waitcnt
// (pipelined polling: caller manages vmcnt).
__device__ __forceinline__ void ld3_issue(const ull* p, ull& a, ull& b, ull& c) {
  asm volatile(
      "global_load_dwordx2 %0, %3, off sc0\n\t"
      "global_load_dwordx2 %1, %3, off offset:256 sc0\n\t"
      "global_load_dwordx2 %2, %3, off offset:512 sc0"
      : "=&v"(a), "=&v"(b), "=&v"(c) : "v"(p) : "memory");
}
// wait until <=3 loads outstanding; data threaded via "+v" for SSA ordering.
__device__ __forceinline__ void wait3_touch(ull& a, ull& b, ull& c) {
  asm volatile("s_waitcnt vmcnt(3)" : "+v"(a), "+v"(b), "+v"(c) :: "memory");
}
__device__ __forceinline__ void wait_vm0() {
  asm volatile("s_waitcnt vmcnt(0)" ::: "memory");
}
// 3x 8B stores to the three SoA word arrays, fire-and-forget (L2 write-through).
__device__ __forceinline__ void st3_sc0(ull* p, ull a, ull b, ull c) {
  asm volatile(
      "global_store_dwordx2 %3, %0, off sc0\n\t"
      "global_store_dwordx2 %3, %1, off offset:256 sc0\n\t"
      "global_store_dwordx2 %3, %2, off offset:512 sc0"
      :: "v"(a), "v"(b), "v"(c), "v"(p) : "memory");
}

// stage2: select WG winner from red[8][5]; packed words + winning lane
__device__ __forceinline__ void stage2_pack(const unsigned (*red)[5], int lane,
                                            ull tag, ull& w0, ull& w1, ull& w2,
                                            int& ewin) {
  const int e = lane & 7;
  const unsigned d2 = red[e][0];
  const unsigned nn = red[e][1];
  const unsigned mx = umax_low8(d2);
  const ull bb = __ballot(d2 == mx) & 0xFFull;
  if (__popcll(bb) == 1) {
    ewin = __ffsll(bb) - 1;
  } else {
    const unsigned v = (d2 == mx) ? (65535u - nn) : 0u;   // max -> smallest n
    const unsigned mv = umax_low8(v);
    const ull b2 = __ballot((d2 == mx) && (v == mv)) & 0xFFull;
    ewin = __ffsll(b2) - 1;
  }
  const ull k2 = ((ull)d2 << 16) | (ull)(65535u - nn);
  const unsigned xb = red[e][2], yb = red[e][3], zb = red[e][4];
  w0 = (k2 << 16) | tag;
  w1 = ((ull)xb << 32) | ((ull)(yb >> 16) << 16) | tag;
  w2 = ((ull)(yb & 0xFFFFu) << 48) | ((ull)zb << 16) | tag;
}

__global__ __launch_bounds__(TPB, 4)
void fps_kernel(const float* __restrict__ pts, float* __restrict__ out,
                ull* __restrict__ ws) {
  const int wg   = blockIdx.x;   // 0..255
  const int b    = wg >> 5;      // batch: CONTIGUOUS blocks 32b..32b+31 (one XCD)
  const int w    = wg & 31;      // wg within batch, 0..31
  const int tid  = threadIdx.x;
  const int lane = tid & 63;
  const int wave = tid >> 6;     // 0..7

  const float* p = pts + (size_t)b * NPTS * 3;

  float px[PPT], py[PPT], pz[PPT], md[PPT];
#pragma unroll
  for (int i = 0; i < PPT; ++i) {
    const int n = w * (TPB * PPT) + i * TPB + tid;
    px[i] = p[3 * n + 0];
    py[i] = p[3 * n + 1];
    pz[i] = p[3 * n + 2];
    md[i] = 1e10f;               // BIG, matches reference init
  }

  float cx = p[0], cy = p[1], cz = p[2];   // first pick is index 0

  // ws (ull): SoA exchange. Per batch: 2 par x 3 words x 32 wg = 192 ull.
  //   [0 .. 1536)        copy L (sc0/L2)
  //   [1536 .. 3072)     copy I (agent/IF mirror)      -> 24 KiB total.
  ull* baseL = ws + (size_t)b * (2 * 3 * WSTR);
  ull* baseI = ws + (size_t)NB * (2 * 3 * WSTR) + (size_t)b * (2 * 3 * WSTR);

  float* out_idx = out + (size_t)b * NSAMP;
  float* out_smp = out + (size_t)NB * NSAMP + (size_t)b * NSAMP * 3;

  if (w == 0 && tid == 0) {
    out_idx[0] = 0.0f;
    out_smp[0] = cx; out_smp[1] = cy; out_smp[2] = cz;
  }

  __shared__ unsigned red[NWAVE][5];  // per-wave {dist_bits, n, x, y, z}; stride 5
                                      // -> banks (e*5)%32 distinct for e<8

  bool useIF = false;                 // permanent fallback to IF polling

  for (int t = 0; t < NSAMP - 1; ++t) {
    // ---- local distance update + thread-local best (value+index only) ----
    float bv = -1.0f; int bi = 0;
#pragma unroll
    for (int i = 0; i < PPT; ++i) {
      const float dx = __fsub_rn(px[i], cx);
      const float dy = __fsub_rn(py[i], cy);
      const float dz = __fsub_rn(pz[i], cz);
      const float d  = __fadd_rn(__fadd_rn(__fmul_rn(dx, dx), __fmul_rn(dy, dy)),
                                 __fmul_rn(dz, dz));
      const float m = fminf(md[i], d);
      md[i] = m;
      if (m > bv) { bv = m; bi = i; }  // strict > keeps earliest i on ties
    }

    // ---- stage1: DPP wave64 max + ballot argmax ----
    const unsigned dbits = __float_as_uint(bv);   // bv>=0: bits order as uint
    const unsigned mw = umax_wave64(dbits);
    const bool tied = (dbits == mw);
    const ull bal0 = __ballot(tied);
    int wlane;
    if (__popcll(bal0) == 1) {
      wlane = __ffsll(bal0) - 1;
    } else {
      // exact first-occurrence: smallest (bi, lane) among tied lanes
      ull sel = 0;
#pragma unroll
      for (int ii = 0; ii < PPT; ++ii) {
        const ull bb = __ballot(tied && (bi == ii));
        const bool take = (sel == 0) && (bb != 0);
        sel = take ? bb : sel;
      }
      wlane = __ffsll(sel) - 1;
    }
    if (lane == wlane) {
      // recover xyz of point bi via cndmask tree (only this lane pays)
      const bool c1 = (bi & 1), c2 = (bi & 2);
      const float qx = c2 ? (c1 ? px[3] : px[2]) : (c1 ? px[1] : px[0]);
      const float qy = c2 ? (c1 ? py[3] : py[2]) : (c1 ? py[1] : py[0]);
      const float qz = c2 ? (c1 ? pz[3] : pz[2]) : (c1 ? pz[1] : pz[0]);
      red[wave][0] = dbits;
      red[wave][1] = (unsigned)(w * (TPB * PPT) + bi * TPB + tid);
      red[wave][2] = __float_as_uint(qx);
      red[wave][3] = __float_as_uint(qy);
      red[wave][4] = __float_as_uint(qz);
    }
    __syncthreads();  // barrier1 (8 waves) — the ONLY barrier per iteration

    const ull tag = (ull)(unsigned)(t + 1);   // 1..1023; stale/zero never matches
    const int par = t & 1;

    if (wave == 1) {
      // ---- publisher: stage2, sc0 publish (L2), IF mirror ----
      // Store drain happens at the NEXT barrier1, hidden under poll+distance.
      ull w0, w1, w2; int ewin;
      stage2_pack(red, lane, tag, w0, w1, w2, ewin);
      if (lane == ewin) {
        ull* slotL = baseL + (size_t)par * (3 * WSTR) + w;
        st3_sc0(slotL, w0, w1, w2);
        ull* slotI = baseI + (size_t)par * (3 * WSTR) + w;
        __hip_atomic_store(slotI,            w0, __ATOMIC_RELAXED, __HIP_MEMORY_SCOPE_AGENT);
        __hip_atomic_store(slotI + WSTR,     w1, __ATOMIC_RELAXED, __HIP_MEMORY_SCOPE_AGENT);
        __hip_atomic_store(slotI + 2 * WSTR, w2, __ATOMIC_RELAXED, __HIP_MEMORY_SCOPE_AGENT);
      }
    }

    // ---- EVERY wave: poll the 32 records, reduce to the global winner ----
    const size_t roff = (size_t)par * (3 * WSTR) + (size_t)(lane & 31);
    const ull* recL = baseL + roff;
    const ull* recI = baseI + roff;
    const bool mine = (lane < WPB);
    ull r0 = 0, r1 = 0, r2 = 0;
    bool s = !mine;     // per-lane success of the fast path

    if (!useIF) {
      // ---- pipelined sc0/L2 poll: two 3-load sets in flight ----
      if (mine) {
        ull a0, a1, a2, b0, b1, b2;
        bool fromA = true, hit = false;
        ld3_issue(recL, a0, a1, a2);
        for (int it = 0; it < 128; ++it) {
          ld3_issue(recL, b0, b1, b2);
          wait3_touch(a0, a1, a2);          // A landed (B in flight)
          bool m = ((a0 & 0xFFFFull) == tag) & ((a1 & 0xFFFFull) == tag) &
                   ((a2 & 0xFFFFull) == tag);
          if (__all(m)) { hit = true; fromA = true; break; }
          ld3_issue(recL, a0, a1, a2);
          wait3_touch(b0, b1, b2);          // B landed (A in flight)
          m = ((b0 & 0xFFFFull) == tag) & ((b1 & 0xFFFFull) == tag) &
              ((b2 & 0xFFFFull) == tag);
          if (__all(m)) { hit = true; fromA = false; break; }
        }
        wait_vm0();                         // drain strays before reg reuse
        if (hit) {
          if (fromA) { r0 = a0; r1 = a1; r2 = a2; }
          else       { r0 = b0; r1 = b1; r2 = b2; }
          s = true;
        }
      }
    }

    if (!__all(s)) {
      // ---- slow path: agent-scope IF polling (placement-independent) ----
      useIF = true;                          // uniform: all lanes set it
      bool done = !mine;
      for (;;) {
        if (!done) {
          r0 = __hip_atomic_load(recI,            __ATOMIC_RELAXED, __HIP_MEMORY_SCOPE_AGENT);
          r1 = __hip_atomic_load(recI + WSTR,     __ATOMIC_RELAXED, __HIP_MEMORY_SCOPE_AGENT);
          r2 = __hip_atomic_load(recI + 2 * WSTR, __ATOMIC_RELAXED, __HIP_MEMORY_SCOPE_AGENT);
          done = ((r0 & 0xFFFFull) == tag) & ((r1 & 0xFFFFull) == tag) &
                 ((r2 & 0xFFFFull) == tag);
        }
        if (__all(done)) break;
        __builtin_amdgcn_s_sleep(1);
      }
    }

    // ---- stage3: full wave64 DPP max + ballot over 32 records (lanes
    //      32..63 hold zeroed records -> never win on real data; ffs picks
    //      the lower lane; value-based n-tie ballots are duplicate-safe) ----
    const unsigned d3  = (unsigned)(r0 >> 32);                 // dist bits
    const unsigned lnv = (unsigned)((r0 >> 16) & 0xFFFFull);   // 65535-n
    const unsigned m3 = umax_wave64(d3);
    const ull b3 = __ballot(d3 == m3);
    int src;
    if (__popcll(b3) == 1) {
      src = __ffsll(b3) - 1;
    } else {
      const unsigned v = (d3 == m3) ? lnv : 0u;                // max -> smallest n
      const unsigned mv = umax_wave64(v);
      const ull b4 = __ballot((d3 == m3) && (v == mv));
      src = __ffsll(b4) - 1;
    }
    const float xx = __uint_as_float((unsigned)(r1 >> 32));
    const float yy = __uint_as_float(((unsigned)((r1 >> 16) & 0xFFFFull) << 16) |
                                     (unsigned)(r2 >> 48));
    const float zz = __uint_as_float((unsigned)((r2 >> 16) & 0xFFFFFFFFull));
    const int n2   = 65535 - (int)__shfl((int)lnv, src, 64);
    const float wx = __shfl(xx, src, 64);
    const float wy = __shfl(yy, src, 64);
    const float wz = __shfl(zz, src, 64);

    // ---- output store (one thread; drains at its next barrier1, hidden) ----
    if (w == 0 && wave == 2 && lane == 0) {
      out_idx[t + 1] = (float)n2;            // exact in fp32
      out_smp[(t + 1) * 3 + 0] = wx;
      out_smp[(t + 1) * 3 + 1] = wy;
      out_smp[(t + 1) * 3 + 2] = wz;
    }
    cx = wx; cy = wy; cz = wz;
  }
}

extern "C" void kernel_launch(void* const* d_in, const int* in_sizes, int n_in,
                              void* d_out, int out_size, void* d_ws, size_t ws_size,
                              hipStream_t stream) {
  (void)in_sizes; (void)n_in; (void)out_size; (void)ws_size;
  const float* pts = (const float*)d_in[0];
  float* out = (float*)d_out;
  ull* ws = (ull*)d_ws;
  fps_kernel<<<dim3(NB * WPB), dim3(TPB), 0, stream>>>(pts, out, ws);
}

// Round 2
// 2739.103 us; speedup vs baseline: 1.3014x; 1.3014x over previous
//
#include <hip/hip_runtime.h>

// FPS: input [8, 65536, 3] f32 -> (idx [8,1024] as f32 values, sampled [8,1024,3] f32)
// concatenated flat in d_out.
//
// R16 = R14 proven protocol (single poller wave0, barrier2 + LDS broadcast,
// publisher wave1 with sc0/L2 copy + agent-scope IF mirror, pipelined polls
// with IF fallback, DPP reduces) + two surgical deltas:
//   1. SoA exchange layout: three contiguous 32x8B word arrays per
//      (batch,parity) instead of 128B-stride AoS records. Poller's 32-lane
//      loads coalesce 32->4 TCC requests per instruction (96->12 per poll
//      round); publishers share lines (8 records/line) so the IF-mirror
//      write-back merges (predicted WRITE_SIZE 24.7MB -> ~8MB).
//   2. barrier2 is a RAW s_barrier (no implicit vmcnt(0) drain): wave1's
//      agent-scope mirror stores (~600-900cy to coherence point) no longer
//      gate the workgroup; they drain at barrier1(t+1)'s __syncthreads,
//      hidden under the distance update. Wave0 issues an explicit
//      s_waitcnt lgkmcnt(0) after writing bc4/bn2 so the LDS broadcast is
//      visible across the raw barrier.
//      Mirror issue stays PRE-barrier2 (post-barrier2 would deadlock the
//      all-IF fallback: barrier2 would wait on the mirror it gates).
//      Slot reuse at t+2 remains ordered: barrier1 fully drains vmcnt, so
//      store(t) completes before store(t+2) is issued (same wave).
//
// R15 post-mortem (reverted): 8 polling waves/WG octupled the sc0 request
// rate on the hot exchange lines; publisher stores fought the storm,
// visibility latency grew past the timeout -> sticky IF mode (34ms outlier).
// Single poller + LDS broadcast is load-bearing.
//
// Ties resolve to the smallest global index (numpy argmax first-occurrence);
// distances are uncontracted fp32 in reference order -> bit-exact.
// Records: 3x 8B self-tagged words (round tag in low16 of each), parity
// double-buffered; stale L2 lines can't fake a future tag; per-word tags
// make mixed-age words harmless. IF fallback (wave-uniform, 128-double-iter
// timeout) keeps correctness independent of block->XCD placement.

#define NB    8
#define NPTS  65536
#define NSAMP 1024
#define WPB   32     // workgroups per batch (one XCD at 256 blocks)
#define TPB   512    // threads per workgroup (8 waves)
#define NWAVE 8
#define PPT   4      // points per thread (WPB*TPB*PPT == NPTS)
#define WSTR  32     // ull stride between the 3 word-arrays of one parity slot

typedef unsigned long long ull;

#define DPP(x, ctrl) \
  ((unsigned)__builtin_amdgcn_update_dpp((int)(x), (int)(x), (ctrl), 0xf, 0xf, false))

// max over 64 lanes -> uniform; row_shr:N = 0x110|N, bcast15=0x142, bcast31=0x143
__device__ __forceinline__ unsigned umax_wave64(unsigned x) {
  unsigned t;
  t = DPP(x, 0x111); x = t > x ? t : x;
  t = DPP(x, 0x112); x = t > x ? t : x;
  t = DPP(x, 0x114); x = t > x ? t : x;
  t = DPP(x, 0x118); x = t > x ? t : x;
  t = DPP(x, 0x142); x = t > x ? t : x;   // bcast15: row r lane15 -> row r+1
  t = DPP(x, 0x143); x = t > x ? t : x;   // bcast31: lane31 -> rows 2,3
  return (unsigned)__builtin_amdgcn_readlane((int)x, 63);
}
// max over lanes 0..7 -> uniform via lane7 (groups of 16 see their row's shr)
__device__ __forceinline__ unsigned umax_low8(unsigned x) {
  unsigned t;
  t = DPP(x, 0x111); x = t > x ? t : x;
  t = DPP(x, 0x112); x = t > x ? t : x;
  t = DPP(x, 0x114); x = t > x ? t : x;
  return (unsigned)__builtin_amdgcn_readlane((int)x, 7);
}

// 3x 8B loads from the three SoA word arrays (+0, +256B, +512B), NO waitcnt
// (pipelined polling: caller manages vmcnt).
__device__ __forceinline__ void ld3_issue(const ull* p, ull& a, ull& b, ull& c) {
  asm volatile(
      "global_load_dwordx2 %0, %3, off sc0\n\t"
      "global_load_dwordx2 %1, %3, off offset:256 sc0\n\t"
      "global_load_dwordx2 %2, %3, off offset:512 sc0"
      : "=&v"(a), "=&v"(b), "=&v"(c) : "v"(p) : "memory");
}
// wait until <=3 loads outstanding; data threaded via "+v" for SSA ordering.
__device__ __forceinline__ void wait3_touch(ull& a, ull& b, ull& c) {
  asm volatile("s_waitcnt vmcnt(3)" : "+v"(a), "+v"(b), "+v"(c) :: "memory");
}
__device__ __forceinline__ void wait_vm0() {
  asm volatile("s_waitcnt vmcnt(0)" ::: "memory");
}
// 3x 8B stores to the three SoA word arrays, fire-and-forget (L2 write-through).
__device__ __forceinline__ void st3_sc0(ull* p, ull a, ull b, ull c) {
  asm volatile(
      "global_store_dwordx2 %3, %0, off sc0\n\t"
      "global_store_dwordx2 %3, %1, off offset:256 sc0\n\t"
      "global_store_dwordx2 %3, %2, off offset:512 sc0"
      :: "v"(a), "v"(b), "v"(c), "v"(p) : "memory");
}

// stage2: select WG winner from red[8][5]; packed words + winning lane
__device__ __forceinline__ void stage2_pack(const unsigned (*red)[5], int lane,
                                            ull tag, ull& w0, ull& w1, ull& w2,
                                            int& ewin) {
  const int e = lane & 7;
  const unsigned d2 = red[e][0];
  const unsigned nn = red[e][1];
  const unsigned mx = umax_low8(d2);
  const ull bb = __ballot(d2 == mx) & 0xFFull;
  if (__popcll(bb) == 1) {
    ewin = __ffsll(bb) - 1;
  } else {
    const unsigned v = (d2 == mx) ? (65535u - nn) : 0u;   // max -> smallest n
    const unsigned mv = umax_low8(v);
    const ull b2 = __ballot((d2 == mx) && (v == mv)) & 0xFFull;
    ewin = __ffsll(b2) - 1;
  }
  const ull k2 = ((ull)d2 << 16) | (ull)(65535u - nn);
  const unsigned xb = red[e][2], yb = red[e][3], zb = red[e][4];
  w0 = (k2 << 16) | tag;
  w1 = ((ull)xb << 32) | ((ull)(yb >> 16) << 16) | tag;
  w2 = ((ull)(yb & 0xFFFFu) << 48) | ((ull)zb << 16) | tag;
}

__global__ __launch_bounds__(TPB, 4)
void fps_kernel(const float* __restrict__ pts, float* __restrict__ out,
                ull* __restrict__ ws) {
  const int wg   = blockIdx.x;   // 0..255
  const int b    = wg >> 5;      // batch: CONTIGUOUS blocks 32b..32b+31 (one XCD)
  const int w    = wg & 31;      // wg within batch, 0..31
  const int tid  = threadIdx.x;
  const int lane = tid & 63;
  const int wave = tid >> 6;     // 0..7

  const float* p = pts + (size_t)b * NPTS * 3;

  float px[PPT], py[PPT], pz[PPT], md[PPT];
#pragma unroll
  for (int i = 0; i < PPT; ++i) {
    const int n = w * (TPB * PPT) + i * TPB + tid;
    px[i] = p[3 * n + 0];
    py[i] = p[3 * n + 1];
    pz[i] = p[3 * n + 2];
    md[i] = 1e10f;               // BIG, matches reference init
  }

  float cx = p[0], cy = p[1], cz = p[2];   // first pick is index 0

  // ws (ull): SoA exchange. Per batch: 2 par x 3 words x 32 wg = 192 ull.
  //   [0 .. 1536)        copy L (sc0/L2)
  //   [1536 .. 3072)     copy I (agent/IF mirror)      -> 24 KiB total.
  ull* baseL = ws + (size_t)b * (2 * 3 * WSTR);
  ull* baseI = ws + (size_t)NB * (2 * 3 * WSTR) + (size_t)b * (2 * 3 * WSTR);

  float* out_idx = out + (size_t)b * NSAMP;
  float* out_smp = out + (size_t)NB * NSAMP + (size_t)b * NSAMP * 3;

  if (w == 0 && tid == 0) {
    out_idx[0] = 0.0f;
    out_smp[0] = cx; out_smp[1] = cy; out_smp[2] = cz;
  }

  __shared__ unsigned red[NWAVE][5];  // per-wave {dist_bits, n, x, y, z}; stride 5
                                      // -> banks (e*5)%32 distinct for e<8
  __shared__ float4 bc4;              // winner xyz (single b128 broadcast)
  __shared__ int bn2;                 // winner index

  bool useIF = false;                 // permanent fallback to IF polling

  for (int t = 0; t < NSAMP - 1; ++t) {
    // ---- local distance update + thread-local best (value+index only) ----
    float bv = -1.0f; int bi = 0;
#pragma unroll
    for (int i = 0; i < PPT; ++i) {
      const float dx = __fsub_rn(px[i], cx);
      const float dy = __fsub_rn(py[i], cy);
      const float dz = __fsub_rn(pz[i], cz);
      const float d  = __fadd_rn(__fadd_rn(__fmul_rn(dx, dx), __fmul_rn(dy, dy)),
                                 __fmul_rn(dz, dz));
      const float m = fminf(md[i], d);
      md[i] = m;
      if (m > bv) { bv = m; bi = i; }  // strict > keeps earliest i on ties
    }

    // ---- stage1: DPP wave64 max + ballot argmax ----
    const unsigned dbits = __float_as_uint(bv);   // bv>=0: bits order as uint
    const unsigned mw = umax_wave64(dbits);
    const bool tied = (dbits == mw);
    const ull bal0 = __ballot(tied);
    int wlane;
    if (__popcll(bal0) == 1) {
      wlane = __ffsll(bal0) - 1;
    } else {
      // exact first-occurrence: smallest (bi, lane) among tied lanes
      ull sel = 0;
#pragma unroll
      for (int ii = 0; ii < PPT; ++ii) {
        const ull bb = __ballot(tied && (bi == ii));
        const bool take = (sel == 0) && (bb != 0);
        sel = take ? bb : sel;
      }
      wlane = __ffsll(sel) - 1;
    }
    if (lane == wlane) {
      // recover xyz of point bi via cndmask tree (only this lane pays)
      const bool c1 = (bi & 1), c2 = (bi & 2);
      const float qx = c2 ? (c1 ? px[3] : px[2]) : (c1 ? px[1] : px[0]);
      const float qy = c2 ? (c1 ? py[3] : py[2]) : (c1 ? py[1] : py[0]);
      const float qz = c2 ? (c1 ? pz[3] : pz[2]) : (c1 ? pz[1] : pz[0]);
      red[wave][0] = dbits;
      red[wave][1] = (unsigned)(w * (TPB * PPT) + bi * TPB + tid);
      red[wave][2] = __float_as_uint(qx);
      red[wave][3] = __float_as_uint(qy);
      red[wave][4] = __float_as_uint(qz);
    }
    __syncthreads();  // barrier1 (8 waves; full drain — orders slot reuse)

    const ull tag = (ull)(unsigned)(t + 1);   // 1..1023; stale/zero never matches
    const int par = t & 1;

    if (wave == 1) {
      // ---- publisher: stage2, sc0 publish (L2), IF mirror (pre-barrier2;
      //      drains at barrier1(t+1), hidden under distance update) ----
      ull w0, w1, w2; int ewin;
      stage2_pack(red, lane, tag, w0, w1, w2, ewin);
      if (lane == ewin) {
        ull* slotL = baseL + (size_t)par * (3 * WSTR) + w;
        st3_sc0(slotL, w0, w1, w2);
        ull* slotI = baseI + (size_t)par * (3 * WSTR) + w;
        __hip_atomic_store(slotI,            w0, __ATOMIC_RELAXED, __HIP_MEMORY_SCOPE_AGENT);
        __hip_atomic_store(slotI + WSTR,     w1, __ATOMIC_RELAXED, __HIP_MEMORY_SCOPE_AGENT);
        __hip_atomic_store(slotI + 2 * WSTR, w2, __ATOMIC_RELAXED, __HIP_MEMORY_SCOPE_AGENT);
      }
    } else if (wave == 0) {
      const size_t roff = (size_t)par * (3 * WSTR) + (size_t)(lane & 31);
      const ull* recL = baseL + roff;
      const ull* recI = baseI + roff;
      const bool mine = (lane < WPB);
      ull r0 = 0, r1 = 0, r2 = 0;
      bool s = !mine;     // per-lane success of the fast path

      if (!useIF) {
        // ---- pipelined sc0/L2 poll: two 3-load sets in flight ----
        if (mine) {
          ull a0, a1, a2, b0, b1, b2;
          bool fromA = true, hit = false;
          ld3_issue(recL, a0, a1, a2);
          for (int it = 0; it < 128; ++it) {
            ld3_issue(recL, b0, b1, b2);
            wait3_touch(a0, a1, a2);          // A landed (B in flight)
            bool m = ((a0 & 0xFFFFull) == tag) & ((a1 & 0xFFFFull) == tag) &
                     ((a2 & 0xFFFFull) == tag);
            if (__all(m)) { hit = true; fromA = true; break; }
            ld3_issue(recL, a0, a1, a2);
            wait3_touch(b0, b1, b2);          // B landed (A in flight)
            m = ((b0 & 0xFFFFull) == tag) & ((b1 & 0xFFFFull) == tag) &
                ((b2 & 0xFFFFull) == tag);
            if (__all(m)) { hit = true; fromA = false; break; }
          }
          wait_vm0();                         // drain strays before reg reuse
          if (hit) {
            if (fromA) { r0 = a0; r1 = a1; r2 = a2; }
            else       { r0 = b0; r1 = b1; r2 = b2; }
            s = true;
          }
        }
      }

      if (!__all(s)) {
        // ---- slow path: agent-scope IF polling (placement-independent) ----
        useIF = true;                          // uniform: all lanes set it
        bool done = !mine;
        for (;;) {
          if (!done) {
            r0 = __hip_atomic_load(recI,            __ATOMIC_RELAXED, __HIP_MEMORY_SCOPE_AGENT);
            r1 = __hip_atomic_load(recI + WSTR,     __ATOMIC_RELAXED, __HIP_MEMORY_SCOPE_AGENT);
            r2 = __hip_atomic_load(recI + 2 * WSTR, __ATOMIC_RELAXED, __HIP_MEMORY_SCOPE_AGENT);
            done = ((r0 & 0xFFFFull) == tag) & ((r1 & 0xFFFFull) == tag) &
                   ((r2 & 0xFFFFull) == tag);
          }
          if (__all(done)) break;
          __builtin_amdgcn_s_sleep(1);
        }
      }

      // ---- stage3: full wave64 DPP max + ballot over 32 records (lanes
      //      32..63 hold zeroed records -> never win; ffs picks the lower
      //      lane; value-based n-tie ballots are duplicate-safe) ----
      const unsigned d3  = (unsigned)(r0 >> 32);                 // dist bits
      const unsigned lnv = (unsigned)((r0 >> 16) & 0xFFFFull);   // 65535-n
      const unsigned m3 = umax_wave64(d3);
      const ull b3 = __ballot(d3 == m3);
      int src;
      if (__popcll(b3) == 1) {
        src = __ffsll(b3) - 1;
      } else {
        const unsigned v = (d3 == m3) ? lnv : 0u;                // max -> smallest n
        const unsigned mv = umax_wave64(v);
        const ull b4 = __ballot((d3 == m3) && (v == mv));
        src = __ffsll(b4) - 1;
      }
      const float xx = __uint_as_float((unsigned)(r1 >> 32));
      const float yy = __uint_as_float(((unsigned)((r1 >> 16) & 0xFFFFull) << 16) |
                                       (unsigned)(r2 >> 48));
      const float zz = __uint_as_float((unsigned)((r2 >> 16) & 0xFFFFFFFFull));
      const int n2   = 65535 - (int)__shfl((int)lnv, src, 64);
      const float wx = __shfl(xx, src, 64);
      const float wy = __shfl(yy, src, 64);
      const float wz = __shfl(zz, src, 64);
      if (lane == 0) {
        bc4 = make_float4(wx, wy, wz, 0.0f);   // single ds_write_b128
        bn2 = n2;
      }
      // make the LDS broadcast visible before the RAW barrier below
      asm volatile("s_waitcnt lgkmcnt(0)" ::: "memory");
    }
    // barrier2: RAW s_barrier — no vmcnt(0) drain, so wave1's in-flight
    // IF-mirror stores don't gate the workgroup. LDS ordering guaranteed by
    // wave0's explicit lgkmcnt(0) above; compiler reordering blocked by the
    // "memory" clobber.
    asm volatile("s_barrier" ::: "memory");

    // ---- deferred output store (off the critical path) ----
    const float4 c4 = bc4;                     // single ds_read_b128
    if (w == 0 && wave == 2 && lane == 0) {
      out_idx[t + 1] = (float)bn2;             // exact in fp32
      out_smp[(t + 1) * 3 + 0] = c4.x;
      out_smp[(t + 1) * 3 + 1] = c4.y;
      out_smp[(t + 1) * 3 + 2] = c4.z;
    }
    cx = c4.x; cy = c4.y; cz = c4.z;
  }
}

extern "C" void kernel_launch(void* const* d_in, const int* in_sizes, int n_in,
                              void* d_out, int out_size, void* d_ws, size_t ws_size,
                              hipStream_t stream) {
  (void)in_sizes; (void)n_in; (void)out_size; (void)ws_size;
  const float* pts = (const float*)d_in[0];
  float* out = (float*)d_out;
  ull* ws = (ull*)d_ws;
  fps_kernel<<<dim3(NB * WPB), dim3(TPB), 0, stream>>>(pts, out, ws);
}

// Round 3
// 2633.657 us; speedup vs baseline: 1.3535x; 1.0400x over previous
//
#include <hip/hip_runtime.h>

// FPS: input [8, 65536, 3] f32 -> (idx [8,1024] as f32 values, sampled [8,1024,3] f32)
// concatenated flat in d_out.
//
// R17 = R14 proven protocol (single poller wave0, __syncthreads barrier2 +
// LDS broadcast, publisher wave1, pipelined polls, IF fallback, DPP reduces,
// AoS one-record-per-line) + ONE lever: a tiered L2-resident fast path.
//
// Evidence (R14 counters): FETCH_SIZE ~135 KB/iter + WRITE_SIZE ~24 KB/iter
// == the sc0 exchange round-trips through the memory side EVERY iteration
// (sc0 stores write through past L2; polls then miss L2 and fetch from IF,
// ~1000+cy visibility — about half the 4900cy iteration).
// Fix attempt: all 32 WGs of a batch share ONE physical XCD L2 (R6-verified
// placement). A PLAIN store is write-back -> lands and stays dirty in that
// shared L2; an sc0 load bypasses L1 only -> should hit L2 (~400-500cy
// visibility, no HBM fetch).
// Unknown: whether gfx950 sc0 loads can hit L2 at all. So TIERED:
//   publisher writes the record to 3 regions: P (plain store), L (sc0,
//   R14-proven), I (agent-scope mirror).
//   poller: tier0 polls P (40 rounds) -> on timeout demote PERMANENTLY to
//   tier1 = poll L (128 rounds, exact R14) -> on timeout sticky IF fallback.
// Worst case = R14 + ~16us one-time demote. Best case removes the memory-
// side round trip per iteration.
//
// R15/R16 post-mortem (reverted): SoA shared-line exchange serialized
// publisher stores against the aggregate poll stream (FETCH dropped but dur
// rose) — AoS one-record-per-line is load-bearing. Records are 64B now
// (RECQ=8) so P+L+I fit in 96 KiB of workspace.
//
// Ties resolve to the smallest global index (numpy argmax first-occurrence);
// distances are uncontracted fp32 in reference order -> bit-exact.
// Records: 3x 8B self-tagged words (round tag in low16 of each), parity
// double-buffered; stale L2 lines can't fake a future tag; per-word tags
// make mixed-age words harmless. Slot reuse at t+2 ordered by tag
// transitivity through barrier2 + barrier1's full drain. IF fallback
// (wave-uniform) keeps correctness independent of block->XCD placement.

#define NB    8
#define NPTS  65536
#define NSAMP 1024
#define WPB   32     // workgroups per batch (one XCD at 256 blocks)
#define TPB   512    // threads per workgroup (8 waves)
#define NWAVE 8
#define PPT   4      // points per thread (WPB*TPB*PPT == NPTS)
#define RECQ  8      // 8 ull = 64 B per record line (one line per record)

typedef unsigned long long ull;

#define DPP(x, ctrl) \
  ((unsigned)__builtin_amdgcn_update_dpp((int)(x), (int)(x), (ctrl), 0xf, 0xf, false))

// max over 64 lanes -> uniform; row_shr:N = 0x110|N, bcast15=0x142, bcast31=0x143
__device__ __forceinline__ unsigned umax_wave64(unsigned x) {
  unsigned t;
  t = DPP(x, 0x111); x = t > x ? t : x;
  t = DPP(x, 0x112); x = t > x ? t : x;
  t = DPP(x, 0x114); x = t > x ? t : x;
  t = DPP(x, 0x118); x = t > x ? t : x;
  t = DPP(x, 0x142); x = t > x ? t : x;   // bcast15: row r lane15 -> row r+1
  t = DPP(x, 0x143); x = t > x ? t : x;   // bcast31: lane31 -> rows 2,3
  return (unsigned)__builtin_amdgcn_readlane((int)x, 63);
}
// max over lanes 0..7 -> uniform via lane7 (groups of 16 see their row's shr)
__device__ __forceinline__ unsigned umax_low8(unsigned x) {
  unsigned t;
  t = DPP(x, 0x111); x = t > x ? t : x;
  t = DPP(x, 0x112); x = t > x ? t : x;
  t = DPP(x, 0x114); x = t > x ? t : x;
  return (unsigned)__builtin_amdgcn_readlane((int)x, 7);
}

// 3x 8B loads (AoS record: +0,+8,+16), sc0 = L1-bypass. NO waitcnt
// (pipelined polling: caller manages vmcnt).
__device__ __forceinline__ void ld3_issue(const ull* p, ull& a, ull& b, ull& c) {
  asm volatile(
      "global_load_dwordx2 %0, %3, off sc0\n\t"
      "global_load_dwordx2 %1, %3, off offset:8 sc0\n\t"
      "global_load_dwordx2 %2, %3, off offset:16 sc0"
      : "=&v"(a), "=&v"(b), "=&v"(c) : "v"(p) : "memory");
}
// wait until <=3 loads outstanding; data threaded via "+v" for SSA ordering.
__device__ __forceinline__ void wait3_touch(ull& a, ull& b, ull& c) {
  asm volatile("s_waitcnt vmcnt(3)" : "+v"(a), "+v"(b), "+v"(c) :: "memory");
}
__device__ __forceinline__ void wait_vm0() {
  asm volatile("s_waitcnt vmcnt(0)" ::: "memory");
}
// 3x 8B PLAIN stores: write-back, line stays dirty in the shared XCD L2.
__device__ __forceinline__ void st3_plain(ull* p, ull a, ull b, ull c) {
  asm volatile(
      "global_store_dwordx2 %3, %0, off\n\t"
      "global_store_dwordx2 %3, %1, off offset:8\n\t"
      "global_store_dwordx2 %3, %2, off offset:16"
      :: "v"(a), "v"(b), "v"(c), "v"(p) : "memory");
}
// 3x 8B sc0 stores (R14-proven publish path; visible to sc0 loads).
__device__ __forceinline__ void st3_sc0(ull* p, ull a, ull b, ull c) {
  asm volatile(
      "global_store_dwordx2 %3, %0, off sc0\n\t"
      "global_store_dwordx2 %3, %1, off offset:8 sc0\n\t"
      "global_store_dwordx2 %3, %2, off offset:16 sc0"
      :: "v"(a), "v"(b), "v"(c), "v"(p) : "memory");
}

// Pipelined poll: two 3-load sets in flight; all 64 lanes (lane&31 duplicate
// addressing -> coalesced; __all over duplicates is equivalent). Returns
// wave-uniform hit; on hit fills r0..r2. Always drains vmcnt before return.
__device__ __forceinline__ bool poll3(const ull* rec, ull tag, int rounds,
                                      ull& r0, ull& r1, ull& r2) {
  ull a0, a1, a2, b0, b1, b2;
  bool fromA = true, hit = false;
  ld3_issue(rec, a0, a1, a2);
  for (int it = 0; it < rounds; ++it) {
    ld3_issue(rec, b0, b1, b2);
    wait3_touch(a0, a1, a2);          // A landed (B in flight)
    bool m = ((a0 & 0xFFFFull) == tag) & ((a1 & 0xFFFFull) == tag) &
             ((a2 & 0xFFFFull) == tag);
    if (__all(m)) { hit = true; fromA = true; break; }
    ld3_issue(rec, a0, a1, a2);
    wait3_touch(b0, b1, b2);          // B landed (A in flight)
    m = ((b0 & 0xFFFFull) == tag) & ((b1 & 0xFFFFull) == tag) &
        ((b2 & 0xFFFFull) == tag);
    if (__all(m)) { hit = true; fromA = false; break; }
  }
  wait_vm0();                         // drain strays before reg reuse
  if (hit) {
    if (fromA) { r0 = a0; r1 = a1; r2 = a2; }
    else       { r0 = b0; r1 = b1; r2 = b2; }
  }
  return hit;
}

// stage2: select WG winner from red[8][5]; packed words + winning lane
__device__ __forceinline__ void stage2_pack(const unsigned (*red)[5], int lane,
                                            ull tag, ull& w0, ull& w1, ull& w2,
                                            int& ewin) {
  const int e = lane & 7;
  const unsigned d2 = red[e][0];
  const unsigned nn = red[e][1];
  const unsigned mx = umax_low8(d2);
  const ull bb = __ballot(d2 == mx) & 0xFFull;
  if (__popcll(bb) == 1) {
    ewin = __ffsll(bb) - 1;
  } else {
    const unsigned v = (d2 == mx) ? (65535u - nn) : 0u;   // max -> smallest n
    const unsigned mv = umax_low8(v);
    const ull b2 = __ballot((d2 == mx) && (v == mv)) & 0xFFull;
    ewin = __ffsll(b2) - 1;
  }
  const ull k2 = ((ull)d2 << 16) | (ull)(65535u - nn);
  const unsigned xb = red[e][2], yb = red[e][3], zb = red[e][4];
  w0 = (k2 << 16) | tag;
  w1 = ((ull)xb << 32) | ((ull)(yb >> 16) << 16) | tag;
  w2 = ((ull)(yb & 0xFFFFu) << 48) | ((ull)zb << 16) | tag;
}

__global__ __launch_bounds__(TPB, 4)
void fps_kernel(const float* __restrict__ pts, float* __restrict__ out,
                ull* __restrict__ ws) {
  const int wg   = blockIdx.x;   // 0..255
  const int b    = wg >> 5;      // batch: CONTIGUOUS blocks 32b..32b+31 (one XCD)
  const int w    = wg & 31;      // wg within batch, 0..31
  const int tid  = threadIdx.x;
  const int lane = tid & 63;
  const int wave = tid >> 6;     // 0..7

  const float* p = pts + (size_t)b * NPTS * 3;

  float px[PPT], py[PPT], pz[PPT], md[PPT];
#pragma unroll
  for (int i = 0; i < PPT; ++i) {
    const int n = w * (TPB * PPT) + i * TPB + tid;
    px[i] = p[3 * n + 0];
    py[i] = p[3 * n + 1];
    pz[i] = p[3 * n + 2];
    md[i] = 1e10f;               // BIG, matches reference init
  }

  float cx = p[0], cy = p[1], cz = p[2];   // first pick is index 0

  // ws (ull): three AoS regions, each NB x 2par x 32wg x RECQ(8) = 4096 ull:
  //   P [0..4096)       plain-store copy (L2-resident fast path)
  //   L [4096..8192)    sc0 copy (R14-proven)
  //   I [8192..12288)   agent-scope IF mirror            -> 96 KiB total.
  ull* baseP = ws + (size_t)b * (2 * WPB * RECQ);
  ull* baseL = ws + (size_t)NB * (2 * WPB * RECQ) + (size_t)b * (2 * WPB * RECQ);
  ull* baseI = ws + (size_t)2 * NB * (2 * WPB * RECQ) + (size_t)b * (2 * WPB * RECQ);

  float* out_idx = out + (size_t)b * NSAMP;
  float* out_smp = out + (size_t)NB * NSAMP + (size_t)b * NSAMP * 3;

  if (w == 0 && tid == 0) {
    out_idx[0] = 0.0f;
    out_smp[0] = cx; out_smp[1] = cy; out_smp[2] = cz;
  }

  __shared__ unsigned red[NWAVE][5];  // per-wave {dist_bits, n, x, y, z}; stride 5
                                      // -> banks (e*5)%32 distinct for e<8
  __shared__ float4 bc4;              // winner xyz (single b128 broadcast)
  __shared__ int bn2;                 // winner index

  int  tier  = 0;      // 0 = poll P (plain/L2), 1 = poll L (sc0) — sticky demote
  bool useIF = false;  // permanent fallback to IF polling

  for (int t = 0; t < NSAMP - 1; ++t) {
    // ---- local distance update + thread-local best (value+index only) ----
    float bv = -1.0f; int bi = 0;
#pragma unroll
    for (int i = 0; i < PPT; ++i) {
      const float dx = __fsub_rn(px[i], cx);
      const float dy = __fsub_rn(py[i], cy);
      const float dz = __fsub_rn(pz[i], cz);
      const float d  = __fadd_rn(__fadd_rn(__fmul_rn(dx, dx), __fmul_rn(dy, dy)),
                                 __fmul_rn(dz, dz));
      const float m = fminf(md[i], d);
      md[i] = m;
      if (m > bv) { bv = m; bi = i; }  // strict > keeps earliest i on ties
    }

    // ---- stage1: DPP wave64 max + ballot argmax ----
    const unsigned dbits = __float_as_uint(bv);   // bv>=0: bits order as uint
    const unsigned mw = umax_wave64(dbits);
    const bool tied = (dbits == mw);
    const ull bal0 = __ballot(tied);
    int wlane;
    if (__popcll(bal0) == 1) {
      wlane = __ffsll(bal0) - 1;
    } else {
      // exact first-occurrence: smallest (bi, lane) among tied lanes
      ull sel = 0;
#pragma unroll
      for (int ii = 0; ii < PPT; ++ii) {
        const ull bb = __ballot(tied && (bi == ii));
        const bool take = (sel == 0) && (bb != 0);
        sel = take ? bb : sel;
      }
      wlane = __ffsll(sel) - 1;
    }
    if (lane == wlane) {
      // recover xyz of point bi via cndmask tree (only this lane pays)
      const bool c1 = (bi & 1), c2 = (bi & 2);
      const float qx = c2 ? (c1 ? px[3] : px[2]) : (c1 ? px[1] : px[0]);
      const float qy = c2 ? (c1 ? py[3] : py[2]) : (c1 ? py[1] : py[0]);
      const float qz = c2 ? (c1 ? pz[3] : pz[2]) : (c1 ? pz[1] : pz[0]);
      red[wave][0] = dbits;
      red[wave][1] = (unsigned)(w * (TPB * PPT) + bi * TPB + tid);
      red[wave][2] = __float_as_uint(qx);
      red[wave][3] = __float_as_uint(qy);
      red[wave][4] = __float_as_uint(qz);
    }
    __syncthreads();  // barrier1 (8 waves; full drain — orders slot reuse)

    const ull tag = (ull)(unsigned)(t + 1);   // 1..1023; poison never matches
    const int par = t & 1;

    if (wave == 1) {
      // ---- publisher: stage2, then publish to P (plain/L2), L (sc0),
      //      I (agent mirror). P first: fast-path priority. ----
      ull w0, w1, w2; int ewin;
      stage2_pack(red, lane, tag, w0, w1, w2, ewin);
      if (lane == ewin) {
        const size_t so = (size_t)(par * WPB + w) * RECQ;
        st3_plain(baseP + so, w0, w1, w2);
        st3_sc0(baseL + so, w0, w1, w2);
        ull* slotI = baseI + so;
        __hip_atomic_store(slotI + 0, w0, __ATOMIC_RELAXED, __HIP_MEMORY_SCOPE_AGENT);
        __hip_atomic_store(slotI + 1, w1, __ATOMIC_RELAXED, __HIP_MEMORY_SCOPE_AGENT);
        __hip_atomic_store(slotI + 2, w2, __ATOMIC_RELAXED, __HIP_MEMORY_SCOPE_AGENT);
      }
    } else if (wave == 0) {
      // ---- poller: tiered. All 64 lanes, lane&31 duplicate addressing. ----
      const size_t roff = (size_t)(par * WPB + (lane & 31)) * RECQ;
      const ull* recP = baseP + roff;
      const ull* recL = baseL + roff;
      const ull* recI = baseI + roff;
      ull r0 = 0, r1 = 0, r2 = 0;
      bool s = false;

      if (tier == 0) {
        s = poll3(recP, tag, 40, r0, r1, r2);
        if (!s) tier = 1;               // sc0 loads can't see plain stores ->
      }                                  // demote permanently (one-time cost)
      if (!s && !useIF) {
        s = poll3(recL, tag, 128, r0, r1, r2);
        if (!s) useIF = true;
      }
      if (!s) {
        // ---- slow path: agent-scope IF polling (placement-independent) ----
        bool done = false;
        for (;;) {
          r0 = __hip_atomic_load(recI + 0, __ATOMIC_RELAXED, __HIP_MEMORY_SCOPE_AGENT);
          r1 = __hip_atomic_load(recI + 1, __ATOMIC_RELAXED, __HIP_MEMORY_SCOPE_AGENT);
          r2 = __hip_atomic_load(recI + 2, __ATOMIC_RELAXED, __HIP_MEMORY_SCOPE_AGENT);
          done = ((r0 & 0xFFFFull) == tag) & ((r1 & 0xFFFFull) == tag) &
                 ((r2 & 0xFFFFull) == tag);
          if (__all(done)) break;
          __builtin_amdgcn_s_sleep(1);
        }
      }

      // ---- stage3: full wave64 DPP max + ballot over 32 records (lanes
      //      32..63 duplicate 0..31; ffs picks the lower lane; value-based
      //      n-tie ballots are duplicate-safe) ----
      const unsigned d3  = (unsigned)(r0 >> 32);                 // dist bits
      const unsigned lnv = (unsigned)((r0 >> 16) & 0xFFFFull);   // 65535-n
      const unsigned m3 = umax_wave64(d3);
      const ull b3 = __ballot(d3 == m3);
      int src;
      if (__popcll(b3) == 1) {
        src = __ffsll(b3) - 1;
      } else {
        const unsigned v = (d3 == m3) ? lnv : 0u;                // max -> smallest n
        const unsigned mv = umax_wave64(v);
        const ull b4 = __ballot((d3 == m3) && (v == mv));
        src = __ffsll(b4) - 1;
      }
      const float xx = __uint_as_float((unsigned)(r1 >> 32));
      const float yy = __uint_as_float(((unsigned)((r1 >> 16) & 0xFFFFull) << 16) |
                                       (unsigned)(r2 >> 48));
      const float zz = __uint_as_float((unsigned)((r2 >> 16) & 0xFFFFFFFFull));
      const int n2   = 65535 - (int)__shfl((int)lnv, src, 64);
      const float wx = __shfl(xx, src, 64);
      const float wy = __shfl(yy, src, 64);
      const float wz = __shfl(zz, src, 64);
      if (lane == 0) {
        bc4 = make_float4(wx, wy, wz, 0.0f);   // single ds_write_b128
        bn2 = n2;
      }
    }
    __syncthreads();  // barrier2 (wave0 has no outstanding stores here)

    // ---- deferred output store (off the critical path) ----
    const float4 c4 = bc4;                     // single ds_read_b128
    if (w == 0 && wave == 2 && lane == 0) {
      out_idx[t + 1] = (float)bn2;             // exact in fp32
      out_smp[(t + 1) * 3 + 0] = c4.x;
      out_smp[(t + 1) * 3 + 1] = c4.y;
      out_smp[(t + 1) * 3 + 2] = c4.z;
    }
    cx = c4.x; cy = c4.y; cz = c4.z;
  }
}

extern "C" void kernel_launch(void* const* d_in, const int* in_sizes, int n_in,
                              void* d_out, int out_size, void* d_ws, size_t ws_size,
                              hipStream_t stream) {
  (void)in_sizes; (void)n_in; (void)out_size; (void)ws_size;
  const float* pts = (const float*)d_in[0];
  float* out = (float*)d_out;
  ull* ws = (ull*)d_ws;
  fps_kernel<<<dim3(NB * WPB), dim3(TPB), 0, stream>>>(pts, out, ws);
}